// Round 5
// baseline (1276.791 us; speedup 1.0000x reference)
//
#include <hip/hip_runtime.h>
#include <math.h>

// Problem constants: B=64, N=14*14*32=6272, DIN=8, D=16, M=10, C=10
#define NPOS 6272
#define DIN_ 8
#define DVEC 16
#define CCAP 10
#define JC 4                    // capsule positions per block (1 per wave)
#define NBLK (NPOS / JC)        // 1568 blocks
#define PSTRIDE 1200            // padded partial row (floats)
#define ACC_FLOATS 1194         // S[160] + T[10] + ubar[64*16]
#define P_OFF 1280              // float offset of partials in ws
#define NREP 32                 // lane-private scatter replicas (rep = lane&31 -> 2-way same-addr)
#define RSTRIDE 171             // words; 171 mod 32 = 11 (odd) -> replicas spread banks

__device__ __forceinline__ uint32_t lds_off(const void* p) {
    return (uint32_t)(uintptr_t)p;   // low 32 bits of generic LDS ptr = LDS byte offset
}

// S[win] += th*u (16), T[win] += th (at +64B). Native ds_add_f32: fire-and-forget.
__device__ __forceinline__ void lds_scatter17(uint32_t ba, const float* u, float th) {
    float t0 = th * u[0],  t1 = th * u[1],  t2 = th * u[2],  t3 = th * u[3];
    float t4 = th * u[4],  t5 = th * u[5],  t6 = th * u[6],  t7 = th * u[7];
    float t8 = th * u[8],  t9 = th * u[9],  t10 = th * u[10], t11 = th * u[11];
    float t12 = th * u[12], t13 = th * u[13], t14 = th * u[14], t15 = th * u[15];
    asm volatile(
        "ds_add_f32 %0, %1\n\t"
        "ds_add_f32 %0, %2 offset:4\n\t"
        "ds_add_f32 %0, %3 offset:8\n\t"
        "ds_add_f32 %0, %4 offset:12\n\t"
        "ds_add_f32 %0, %5 offset:16\n\t"
        "ds_add_f32 %0, %6 offset:20\n\t"
        "ds_add_f32 %0, %7 offset:24\n\t"
        "ds_add_f32 %0, %8 offset:28\n\t"
        "ds_add_f32 %0, %9 offset:32\n\t"
        "ds_add_f32 %0, %10 offset:36\n\t"
        "ds_add_f32 %0, %11 offset:40\n\t"
        "ds_add_f32 %0, %12 offset:44\n\t"
        "ds_add_f32 %0, %13 offset:48\n\t"
        "ds_add_f32 %0, %14 offset:52\n\t"
        "ds_add_f32 %0, %15 offset:56\n\t"
        "ds_add_f32 %0, %16 offset:60\n\t"
        "ds_add_f32 %0, %17 offset:64"
        :
        : "v"(ba), "v"(t0), "v"(t1), "v"(t2), "v"(t3), "v"(t4), "v"(t5), "v"(t6),
          "v"(t7), "v"(t8), "v"(t9), "v"(t10), "v"(t11), "v"(t12), "v"(t13),
          "v"(t14), "v"(t15), "v"(th)
        : "memory");
}

__device__ __forceinline__ void lds_scatter16(uint32_t ba, const float* u) {
    asm volatile(
        "ds_add_f32 %0, %1\n\t"
        "ds_add_f32 %0, %2 offset:4\n\t"
        "ds_add_f32 %0, %3 offset:8\n\t"
        "ds_add_f32 %0, %4 offset:12\n\t"
        "ds_add_f32 %0, %5 offset:16\n\t"
        "ds_add_f32 %0, %6 offset:20\n\t"
        "ds_add_f32 %0, %7 offset:24\n\t"
        "ds_add_f32 %0, %8 offset:28\n\t"
        "ds_add_f32 %0, %9 offset:32\n\t"
        "ds_add_f32 %0, %10 offset:36\n\t"
        "ds_add_f32 %0, %11 offset:40\n\t"
        "ds_add_f32 %0, %12 offset:44\n\t"
        "ds_add_f32 %0, %13 offset:48\n\t"
        "ds_add_f32 %0, %14 offset:52\n\t"
        "ds_add_f32 %0, %15 offset:56\n\t"
        "ds_add_f32 %0, %16 offset:60"
        :
        : "v"(ba), "v"(u[0]), "v"(u[1]), "v"(u[2]), "v"(u[3]), "v"(u[4]), "v"(u[5]),
          "v"(u[6]), "v"(u[7]), "v"(u[8]), "v"(u[9]), "v"(u[10]), "v"(u[11]),
          "v"(u[12]), "v"(u[13]), "v"(u[14]), "v"(u[15])
        : "memory");
}

// tanh(n)/n, branch-free, n >= 0. exp overflow -> rcp(inf)=0 -> tanh=1. OK.
__device__ __forceinline__ float squash_scale(float nsq) {
    float n = __builtin_amdgcn_sqrtf(nsq);
    float e = __expf(2.0f * n);
    float th = 1.0f - 2.0f * __builtin_amdgcn_rcpf(e + 1.0f);
    return th * __builtin_amdgcn_rcpf(n);
}

// ---------------------------------------------------------------------------
// Main kernel. wave wv <-> jj = wv; lane = b; m processed in pairs (ILP).
// Winner accumulation: in-loop ds_add scatter into 32 lane-private replicas
// (2-way same-address only). No 160-reg accumulator (r4's mistake: 212 VGPR
// starved the scheduler at 2 waves/SIMD). No x LDS staging (direct loads).
// ---------------------------------------------------------------------------
__global__ __launch_bounds__(256) void caps_main(
    const float* __restrict__ xin,   // [B][N][8]
    const float* __restrict__ Wg,    // [N][8][160]
    const float* __restrict__ dcg,   // [10][16]
    float* __restrict__ P,           // [NBLK][PSTRIDE] or nullptr
    float* __restrict__ ACC)         // [ACC_FLOATS] (atomic fallback)
{
    __shared__ __align__(16) float W_lds[JC * 1280];   // 20480 B
    __shared__ __align__(16) float dc_lds[160];        // 640 B
    __shared__ float S_rep[NREP * RSTRIDE];            // 21888 B
    __shared__ float ub_lds[64 * 17];                  // 4352 B

    const int tid = threadIdx.x;
    const int j0 = blockIdx.x * JC;
    const int lane = tid & 63;      // = b
    const int wv   = tid >> 6;      // wave id = jj

    // ---- stage W chunk (coalesced float4) ----
    {
        const float4* wsrc = (const float4*)(Wg + (size_t)j0 * 1280);
        float4* wdst = (float4*)W_lds;
        #pragma unroll
        for (int s = 0; s < 5; ++s) wdst[tid + 256 * s] = wsrc[tid + 256 * s];
    }
    if (tid < 40) ((float4*)dc_lds)[tid] = ((const float4*)dcg)[tid];
    for (int q = tid; q < NREP * RSTRIDE; q += 256) S_rep[q] = 0.0f;
    for (int q = tid; q < 64 * 17; q += 256) ub_lds[q] = 0.0f;

    // ---- x row direct from global: 2 float4 per thread (once per block) ----
    float xr[DIN_];
    {
        const float4* xp = (const float4*)(xin + (size_t)lane * (NPOS * DIN_)
                                               + (size_t)(j0 + wv) * DIN_);
        float4 xa = xp[0], xb = xp[1];
        xr[0] = xa.x; xr[1] = xa.y; xr[2] = xa.z; xr[3] = xa.w;
        xr[4] = xb.x; xr[5] = xb.y; xr[6] = xb.z; xr[7] = xb.w;
    }
    __syncthreads();

    const int rep = lane & (NREP - 1);
    const uint32_t sbase = lds_off(&S_rep[rep * RSTRIDE]);

    float ub[DVEC];
    #pragma unroll
    for (int d = 0; d < DVEC; ++d) ub[d] = 0.0f;

    for (int p = 0; p < 5; ++p) {   // m pair {2p, 2p+1}
        // ---- u0, u1 = x (1x8) @ W columns (broadcast b128 W reads) ----
        float u0[DVEC], u1[DVEC];
        #pragma unroll
        for (int d = 0; d < DVEC; ++d) { u0[d] = 0.0f; u1[d] = 0.0f; }
        const float* wbase = &W_lds[wv * 1280 + p * 32];
        #pragma unroll
        for (int i = 0; i < DIN_; ++i) {
            const float4* wr = (const float4*)(wbase + i * 160);
            float xi = xr[i];
            #pragma unroll
            for (int d4 = 0; d4 < 4; ++d4) {
                float4 a = wr[d4];       // m0
                float4 b = wr[d4 + 4];   // m1
                u0[4 * d4 + 0] = fmaf(xi, a.x, u0[4 * d4 + 0]);
                u0[4 * d4 + 1] = fmaf(xi, a.y, u0[4 * d4 + 1]);
                u0[4 * d4 + 2] = fmaf(xi, a.z, u0[4 * d4 + 2]);
                u0[4 * d4 + 3] = fmaf(xi, a.w, u0[4 * d4 + 3]);
                u1[4 * d4 + 0] = fmaf(xi, b.x, u1[4 * d4 + 0]);
                u1[4 * d4 + 1] = fmaf(xi, b.y, u1[4 * d4 + 1]);
                u1[4 * d4 + 2] = fmaf(xi, b.z, u1[4 * d4 + 2]);
                u1[4 * d4 + 3] = fmaf(xi, b.w, u1[4 * d4 + 3]);
            }
        }

        // ---- squash both (tree-reduced norms) ----
        {
            float a0 = fmaf(u0[0], u0[0], u0[1] * u0[1]);
            float a1 = fmaf(u0[2], u0[2], u0[3] * u0[3]);
            float a2 = fmaf(u0[4], u0[4], u0[5] * u0[5]);
            float a3 = fmaf(u0[6], u0[6], u0[7] * u0[7]);
            float a4 = fmaf(u0[8], u0[8], u0[9] * u0[9]);
            float a5 = fmaf(u0[10], u0[10], u0[11] * u0[11]);
            float a6 = fmaf(u0[12], u0[12], u0[13] * u0[13]);
            float a7 = fmaf(u0[14], u0[14], u0[15] * u0[15]);
            float n0 = ((a0 + a1) + (a2 + a3)) + ((a4 + a5) + (a6 + a7));
            float sc0 = squash_scale(n0);
            float b0 = fmaf(u1[0], u1[0], u1[1] * u1[1]);
            float b1 = fmaf(u1[2], u1[2], u1[3] * u1[3]);
            float b2 = fmaf(u1[4], u1[4], u1[5] * u1[5]);
            float b3 = fmaf(u1[6], u1[6], u1[7] * u1[7]);
            float b4 = fmaf(u1[8], u1[8], u1[9] * u1[9]);
            float b5 = fmaf(u1[10], u1[10], u1[11] * u1[11]);
            float b6 = fmaf(u1[12], u1[12], u1[13] * u1[13]);
            float b7 = fmaf(u1[14], u1[14], u1[15] * u1[15]);
            float n1 = ((b0 + b1) + (b2 + b3)) + ((b4 + b5) + (b6 + b7));
            float sc1 = squash_scale(n1);
            #pragma unroll
            for (int d = 0; d < DVEC; ++d) {
                u0[d] *= sc0; u1[d] *= sc1;
                ub[d] += u0[d] + u1[d];
            }
        }

        // ---- sims vs 10 digit caps (dc read once per pair) ----
        float s0[CCAP], s1[CCAP];
        #pragma unroll
        for (int c = 0; c < CCAP; ++c) {
            const float4* dcr = (const float4*)&dc_lds[c * 16];
            float4 d0 = dcr[0], d1 = dcr[1], d2 = dcr[2], d3 = dcr[3];
            float p00 = fmaf(u0[0], d0.x, u0[1] * d0.y);
            float p01 = fmaf(u0[2], d0.z, u0[3] * d0.w);
            float p02 = fmaf(u0[4], d1.x, u0[5] * d1.y);
            float p03 = fmaf(u0[6], d1.z, u0[7] * d1.w);
            float p04 = fmaf(u0[8], d2.x, u0[9] * d2.y);
            float p05 = fmaf(u0[10], d2.z, u0[11] * d2.w);
            float p06 = fmaf(u0[12], d3.x, u0[13] * d3.y);
            float p07 = fmaf(u0[14], d3.z, u0[15] * d3.w);
            s0[c] = ((p00 + p01) + (p02 + p03)) + ((p04 + p05) + (p06 + p07));
            float p10 = fmaf(u1[0], d0.x, u1[1] * d0.y);
            float p11 = fmaf(u1[2], d0.z, u1[3] * d0.w);
            float p12 = fmaf(u1[4], d1.x, u1[5] * d1.y);
            float p13 = fmaf(u1[6], d1.z, u1[7] * d1.w);
            float p14 = fmaf(u1[8], d2.x, u1[9] * d2.y);
            float p15 = fmaf(u1[10], d2.z, u1[11] * d2.w);
            float p16 = fmaf(u1[12], d3.x, u1[13] * d3.y);
            float p17 = fmaf(u1[14], d3.z, u1[15] * d3.w);
            s1[c] = ((p10 + p11) + (p12 + p13)) + ((p14 + p15) + (p16 + p17));
        }

        // ---- exact reference winner semantics + immediate scatter ----
        // mask in {1,0,-1} via two bitmasks: v = once? (twice? -s : 0) : s
        #pragma unroll
        for (int ev = 0; ev < 2; ++ev) {
            const float* s = (ev == 0) ? s0 : s1;
            const float* u = (ev == 0) ? u0 : u1;
            unsigned once = 0, twice = 0;
            #pragma unroll
            for (int t = 0; t < 3; ++t) {
                float best = -1e30f;
                int win = 0;
                #pragma unroll
                for (int c = 0; c < CCAP; ++c) {
                    float sv = s[c];
                    float v = (once & (1u << c)) ? ((twice & (1u << c)) ? -sv : 0.0f) : sv;
                    if (v > best) { best = v; win = c; }
                }
                twice |= (once & (1u << win));
                once  |= (1u << win);
                const float th = (t == 0) ? 1.0f : (t == 1) ? 0.2f : 0.1f;
                lds_scatter17(sbase + (uint32_t)win * 68u, u, th);
            }
        }
    }

    // per-lane ubar fold (stride-17 rows: 2-way bank alias only, distinct addrs)
    lds_scatter16(lds_off(&ub_lds[lane * 17]), ub);
    __syncthreads();

    // ---- block epilogue: fold 32 replicas, emit 1194 partials ----
    // replica layout: 10 rows of 17 (S[c][0..15], T[c] at slot 16)
    if (P != nullptr) {
        float* prow = P + (size_t)blockIdx.x * PSTRIDE;
        for (int qq = tid; qq < ACC_FLOATS; qq += 256) {
            float v;
            if (qq < 160) {
                int c = qq >> 4, d = qq & 15;
                v = 0.0f;
                #pragma unroll
                for (int r = 0; r < NREP; ++r) v += S_rep[r * RSTRIDE + c * 17 + d];
            } else if (qq < 170) {
                int c = qq - 160;
                v = 0.0f;
                #pragma unroll
                for (int r = 0; r < NREP; ++r) v += S_rep[r * RSTRIDE + c * 17 + 16];
            } else {
                int x = qq - 170;
                v = ub_lds[(x >> 4) * 17 + (x & 15)];
            }
            prow[qq] = v;
        }
    } else {
        for (int qq = tid; qq < ACC_FLOATS; qq += 256) {
            float v;
            if (qq < 170) {
                int c = (qq < 160) ? (qq >> 4) : (qq - 160);
                int d = (qq < 160) ? (qq & 15) : 16;
                v = 0.0f;
                #pragma unroll
                for (int r = 0; r < NREP; ++r) v += S_rep[r * RSTRIDE + c * 17 + d];
            } else {
                int x = qq - 170;
                v = ub_lds[(x >> 4) * 17 + (x & 15)];
            }
            unsafeAtomicAdd(&ACC[qq], v);
        }
    }
}

// ---------------------------------------------------------------------------
// Reduce block partials: 98 blocks x 16 rows each, atomic fold to ACC
// ---------------------------------------------------------------------------
__global__ __launch_bounds__(256) void caps_reduce(const float* __restrict__ P,
                                                   float* __restrict__ ACC)
{
    const int t = threadIdx.x;
    float acc[5] = {0.f, 0.f, 0.f, 0.f, 0.f};
    const int r0 = blockIdx.x * 16;
    for (int r = 0; r < 16; ++r) {
        const float* row = P + (size_t)(r0 + r) * PSTRIDE;
        #pragma unroll
        for (int s = 0; s < 5; ++s) {
            int col = t + 256 * s;
            float v = (col < ACC_FLOATS) ? row[col] : 0.0f;
            acc[s] += v;
        }
    }
    #pragma unroll
    for (int s = 0; s < 5; ++s) {
        int col = t + 256 * s;
        if (col < ACC_FLOATS) unsafeAtomicAdd(&ACC[col], acc[s]);
    }
}

// ---------------------------------------------------------------------------
// Finalize: dc update + row-normalize, logits = (ubar/Nm)·dc_new, softmax
// ---------------------------------------------------------------------------
__global__ __launch_bounds__(256) void caps_final(const float* __restrict__ ACC,
                                                  const float* __restrict__ dcg,
                                                  float* __restrict__ outp)
{
    __shared__ float dcn[160];
    __shared__ float rnm[10];
    __shared__ float lg[640];
    const int t = threadIdx.x;

    if (t < 160) {
        int c = t >> 4;
        float d0 = dcg[t];
        float upd = (ACC[t] - ACC[160 + c] * d0) * (float)(1.0 / 4014080.0); // /(B*N*m)
        dcn[t] = d0 + upd;
    }
    __syncthreads();
    if (t < 10) {
        float s = 0.0f;
        #pragma unroll
        for (int d = 0; d < 16; ++d) s += dcn[t * 16 + d] * dcn[t * 16 + d];
        rnm[t] = 1.0f / sqrtf(s);
    }
    __syncthreads();
    if (t < 160) dcn[t] *= rnm[t >> 4];
    __syncthreads();

    for (int q = t; q < 640; q += 256) {
        int b = q / 10, c = q - 10 * b;
        const float* ubp = &ACC[170 + b * 16];
        float s = 0.0f;
        #pragma unroll
        for (int d = 0; d < 16; ++d) s += ubp[d] * dcn[c * 16 + d];
        lg[q] = s * (float)(1.0 / 62720.0);   // mean over Nm
    }
    __syncthreads();
    if (t < 64) {
        float mx = lg[t * 10];
        #pragma unroll
        for (int c = 1; c < 10; ++c) mx = fmaxf(mx, lg[t * 10 + c]);
        float e[10];
        float ssum = 0.0f;
        #pragma unroll
        for (int c = 0; c < 10; ++c) { e[c] = expf(lg[t * 10 + c] - mx); ssum += e[c]; }
        float inv = 1.0f / ssum;
        #pragma unroll
        for (int c = 0; c < 10; ++c) outp[t * 10 + c] = e[c] * inv;
    }
}

extern "C" void kernel_launch(void* const* d_in, const int* in_sizes, int n_in,
                              void* d_out, int out_size, void* d_ws, size_t ws_size,
                              hipStream_t stream)
{
    const float* xin = (const float*)d_in[0];
    const float* Wg  = (const float*)d_in[1];
    const float* dcg = (const float*)d_in[2];
    float* outp = (float*)d_out;
    float* ws = (float*)d_ws;
    float* ACC = ws;

    const size_t need = (size_t)(P_OFF + (size_t)NBLK * PSTRIDE) * sizeof(float);
    float* P = (ws_size >= need) ? (ws + P_OFF) : nullptr;

    hipMemsetAsync(ACC, 0, ACC_FLOATS * sizeof(float), stream);
    caps_main<<<dim3(NBLK), dim3(256), 0, stream>>>(xin, Wg, dcg, P, ACC);
    if (P) caps_reduce<<<dim3(98), dim3(256), 0, stream>>>(P, ACC);
    caps_final<<<dim3(1), dim3(256), 0, stream>>>(ACC, dcg, outp);
}

// Round 6
// 295.679 us; speedup vs baseline: 4.3182x; 4.3182x over previous
//
#include <hip/hip_runtime.h>
#include <hip/hip_fp16.h>
#include <math.h>

// Problem constants: B=64, N=14*14*32=6272, DIN=8, D=16, M=10, C=10
#define NPOS 6272
#define DIN_ 8
#define DVEC 16
#define CCAP 10
#define JC 4                    // capsule positions per block (1 per wave)
#define NBLK (NPOS / JC)        // 1568 blocks
#define PSTRIDE 1200            // padded partial row (floats)
#define ACC_FLOATS 1194         // S[160] + T[10] + ubar[64*16]
#define P_OFF 1280              // float offset of partials in ws

// ---------------------------------------------------------------------------
// 4-lane (quad) cross-lane sums via DPP quad_perm -- pure VALU, no LDS.
// After these, all 4 lanes of each quad hold the quad total.
// ---------------------------------------------------------------------------
__device__ __forceinline__ unsigned qsum_h2(unsigned v) {
    int t = __builtin_amdgcn_mov_dpp((int)v, 0xB1, 0xF, 0xF, true);   // xor 1
    __half2 a = __builtin_bit_cast(__half2, v);
    __half2 b = __builtin_bit_cast(__half2, (unsigned)t);
    a = __hadd2(a, b);
    v = __builtin_bit_cast(unsigned, a);
    t = __builtin_amdgcn_mov_dpp((int)v, 0x4E, 0xF, 0xF, true);        // xor 2
    b = __builtin_bit_cast(__half2, (unsigned)t);
    a = __builtin_bit_cast(__half2, v);
    a = __hadd2(a, b);
    return __builtin_bit_cast(unsigned, a);
}
__device__ __forceinline__ float qsum_f32(float v) {
    int t = __builtin_amdgcn_mov_dpp(__builtin_bit_cast(int, v), 0xB1, 0xF, 0xF, true);
    v += __builtin_bit_cast(float, t);
    t = __builtin_amdgcn_mov_dpp(__builtin_bit_cast(int, v), 0x4E, 0xF, 0xF, true);
    v += __builtin_bit_cast(float, t);
    return v;
}

// tanh(n)/n, branch-free, n >= 0. exp overflow -> rcp(inf)=0 -> tanh=1. OK.
__device__ __forceinline__ float squash_scale(float nsq) {
    float n = __builtin_amdgcn_sqrtf(nsq);
    float e = __expf(2.0f * n);
    float th = 1.0f - 2.0f * __builtin_amdgcn_rcpf(e + 1.0f);
    return th * __builtin_amdgcn_rcpf(n);
}

// ---------------------------------------------------------------------------
// Main kernel. wave <-> j (readfirstlane'd so W streams via s_load to SGPRs);
// lane = b. ZERO LDS atomics: S accumulates densely in packed-fp16 registers
// (80 VGPRs), folded at the end by DPP quad-butterfly + plain ds_writes.
// (Empirical law from r1-r5: each LDS atomic instr costs ~244 cyc serialized;
//  510 of them = the 1270us wall; r4's 186 at the end = 460us of its 615.)
// ---------------------------------------------------------------------------
__global__ __launch_bounds__(256) void caps_main(
    const float* __restrict__ xin,   // [B][N][8]
    const float* __restrict__ Wg,    // [N][8][160]
    const float* __restrict__ dcg,   // [10][16]
    float* __restrict__ P,           // [NBLK][PSTRIDE] or nullptr
    float* __restrict__ ACC)         // [ACC_FLOATS] (atomic fallback)
{
    __shared__ __align__(16) float dc_lds[160];           // 640 B
    __shared__ __align__(16) unsigned S_out[64][90];      // 23040 B: 64 quad-replicas
    __shared__ __align__(16) unsigned ub_out[4][64][8];   // 8192 B: per-(wave,lane)

    const int tid  = threadIdx.x;
    const int lane = tid & 63;                              // = b
    const int wvu  = __builtin_amdgcn_readfirstlane(tid >> 6);  // uniform wave id = jj
    const int j    = blockIdx.x * JC + wvu;

    if (tid < 40) ((float4*)dc_lds)[tid] = ((const float4*)dcg)[tid];

    // x row (per-lane b, per-wave j): 2 float4 direct from global
    float xr[DIN_];
    {
        const float4* xp = (const float4*)(xin + (size_t)lane * (NPOS * DIN_)
                                               + (size_t)j * DIN_);
        float4 xa = xp[0], xb = xp[1];
        xr[0] = xa.x; xr[1] = xa.y; xr[2] = xa.z; xr[3] = xa.w;
        xr[4] = xb.x; xr[5] = xb.y; xr[6] = xb.z; xr[7] = xb.w;
    }
    // wave-uniform W row pointer -> scalar loads (SMEM pipe, no LDS, no VGPR cost)
    const float* __restrict__ wrow = Wg + (size_t)j * 1280;
    __syncthreads();

    // register accumulators
    __half2 S[CCAP][8];                 // 80 VGPRs, packed fp16 pairs
    float   T[CCAP];                    // fp32 (exact-ish theta sums)
    __half2 ub[8];
    #pragma unroll
    for (int c = 0; c < CCAP; ++c) {
        T[c] = 0.0f;
        #pragma unroll
        for (int k = 0; k < 8; ++k) S[c][k] = __float2half2_rn(0.0f);
    }
    #pragma unroll
    for (int k = 0; k < 8; ++k) ub[k] = __float2half2_rn(0.0f);

    #pragma unroll 1
    for (int m = 0; m < 10; ++m) {
        // ---- u[16] = x (1x8) @ W[:, m*16..+16)   W via uniform (scalar) loads ----
        float u[DVEC];
        #pragma unroll
        for (int d = 0; d < DVEC; ++d) u[d] = 0.0f;
        #pragma unroll
        for (int i = 0; i < DIN_; ++i) {
            const float4* wr = (const float4*)(wrow + i * 160 + m * 16);
            float4 a = wr[0], b = wr[1], c = wr[2], d = wr[3];
            float xi = xr[i];
            u[0]  = fmaf(xi, a.x, u[0]);  u[1]  = fmaf(xi, a.y, u[1]);
            u[2]  = fmaf(xi, a.z, u[2]);  u[3]  = fmaf(xi, a.w, u[3]);
            u[4]  = fmaf(xi, b.x, u[4]);  u[5]  = fmaf(xi, b.y, u[5]);
            u[6]  = fmaf(xi, b.z, u[6]);  u[7]  = fmaf(xi, b.w, u[7]);
            u[8]  = fmaf(xi, c.x, u[8]);  u[9]  = fmaf(xi, c.y, u[9]);
            u[10] = fmaf(xi, c.z, u[10]); u[11] = fmaf(xi, c.w, u[11]);
            u[12] = fmaf(xi, d.x, u[12]); u[13] = fmaf(xi, d.y, u[13]);
            u[14] = fmaf(xi, d.z, u[14]); u[15] = fmaf(xi, d.w, u[15]);
        }

        // ---- squash (tree-reduced norm), fp32 ----
        {
            float a0 = fmaf(u[0], u[0], u[1] * u[1]);
            float a1 = fmaf(u[2], u[2], u[3] * u[3]);
            float a2 = fmaf(u[4], u[4], u[5] * u[5]);
            float a3 = fmaf(u[6], u[6], u[7] * u[7]);
            float a4 = fmaf(u[8], u[8], u[9] * u[9]);
            float a5 = fmaf(u[10], u[10], u[11] * u[11]);
            float a6 = fmaf(u[12], u[12], u[13] * u[13]);
            float a7 = fmaf(u[14], u[14], u[15] * u[15]);
            float nsq = ((a0 + a1) + (a2 + a3)) + ((a4 + a5) + (a6 + a7));
            float sc = squash_scale(nsq);
            #pragma unroll
            for (int d = 0; d < DVEC; ++d) u[d] *= sc;
        }

        // ---- pack u to half2 once; accumulate ub (fp16, error negligible) ----
        __half2 uh[8];
        #pragma unroll
        for (int k = 0; k < 8; ++k) {
            uh[k] = __floats2half2_rn(u[2 * k], u[2 * k + 1]);
            ub[k] = __hadd2(ub[k], uh[k]);
        }

        // ---- sims vs 10 digit caps (fp32, dc from LDS, wave-uniform b128) ----
        float s[CCAP];
        #pragma unroll
        for (int c = 0; c < CCAP; ++c) {
            const float4* dcr = (const float4*)&dc_lds[c * 16];
            float4 d0 = dcr[0], d1 = dcr[1], d2 = dcr[2], d3 = dcr[3];
            float p0 = fmaf(u[0], d0.x, u[1] * d0.y);
            float p1 = fmaf(u[2], d0.z, u[3] * d0.w);
            float p2 = fmaf(u[4], d1.x, u[5] * d1.y);
            float p3 = fmaf(u[6], d1.z, u[7] * d1.w);
            float p4 = fmaf(u[8], d2.x, u[9] * d2.y);
            float p5 = fmaf(u[10], d2.z, u[11] * d2.w);
            float p6 = fmaf(u[12], d3.x, u[13] * d3.y);
            float p7 = fmaf(u[14], d3.z, u[15] * d3.w);
            s[c] = ((p0 + p1) + (p2 + p3)) + ((p4 + p5) + (p6 + p7));
        }

        // ---- exact reference winner semantics (mask in {1,0,-1} bitmasks) ----
        int win0, win1, win2;
        {
            unsigned once = 0, twice = 0;
            #pragma unroll
            for (int t = 0; t < 3; ++t) {
                float best = -1e30f;
                int win = 0;
                #pragma unroll
                for (int c = 0; c < CCAP; ++c) {
                    float sv = s[c];
                    float v = (once & (1u << c)) ? ((twice & (1u << c)) ? -sv : 0.0f) : sv;
                    if (v > best) { best = v; win = c; }
                }
                twice |= (once & (1u << win));
                once  |= (1u << win);
                if (t == 0) win0 = win; else if (t == 1) win1 = win; else win2 = win;
            }
        }

        // ---- dense weighted accumulate in packed fp16 ----
        #pragma unroll
        for (int c = 0; c < CCAP; ++c) {
            float w = (win0 == c ? 1.0f : 0.0f);
            w += (win1 == c) ? 0.2f : 0.0f;
            w += (win2 == c) ? 0.1f : 0.0f;
            T[c] += w;
            __half2 wh = __float2half2_rn(w);
            #pragma unroll
            for (int k = 0; k < 8; ++k) S[c][k] = __hfma2(wh, uh[k], S[c][k]);
        }
    }

    // ---- quad-butterfly (DPP, VALU-only) then plain LDS writes ----
    {
        unsigned sq[CCAP][8];
        float tq[CCAP];
        #pragma unroll
        for (int c = 0; c < CCAP; ++c) {
            tq[c] = qsum_f32(T[c]);
            #pragma unroll
            for (int k = 0; k < 8; ++k)
                sq[c][k] = qsum_h2(__builtin_bit_cast(unsigned, S[c][k]));
        }
        if ((lane & 3) == 0) {
            unsigned* row = S_out[wvu * 16 + (lane >> 2)];
            #pragma unroll
            for (int c = 0; c < CCAP; ++c) {
                #pragma unroll
                for (int k = 0; k < 8; ++k) row[c * 8 + k] = sq[c][k];
                row[80 + c] = __builtin_bit_cast(unsigned, tq[c]);
            }
        }
        #pragma unroll
        for (int k = 0; k < 8; ++k)
            ub_out[wvu][lane][k] = __builtin_bit_cast(unsigned, ub[k]);
    }
    __syncthreads();

    // ---- fold 64 quad-replicas + 4 ub waves, emit 1194 fp32 partials ----
    if (P != nullptr) {
        float* prow = P + (size_t)blockIdx.x * PSTRIDE;
        for (int q = tid; q < ACC_FLOATS; q += 256) {
            float v = 0.0f;
            if (q < 160) {
                int wd = (q >> 4) * 8 + ((q & 15) >> 1);
                int hi = q & 1;
                #pragma unroll 8
                for (int r = 0; r < 64; ++r) {
                    __half2 h = __builtin_bit_cast(__half2, S_out[r][wd]);
                    v += hi ? __high2float(h) : __low2float(h);
                }
            } else if (q < 170) {
                #pragma unroll 8
                for (int r = 0; r < 64; ++r)
                    v += __builtin_bit_cast(float, S_out[r][80 + (q - 160)]);
            } else {
                int x = q - 170, b = x >> 4, d = x & 15;
                #pragma unroll
                for (int w2 = 0; w2 < 4; ++w2) {
                    __half2 h = __builtin_bit_cast(__half2, ub_out[w2][b][d >> 1]);
                    v += (d & 1) ? __high2float(h) : __low2float(h);
                }
            }
            prow[q] = v;
        }
    } else {
        for (int q = tid; q < ACC_FLOATS; q += 256) {
            float v = 0.0f;
            if (q < 160) {
                int wd = (q >> 4) * 8 + ((q & 15) >> 1);
                int hi = q & 1;
                #pragma unroll 8
                for (int r = 0; r < 64; ++r) {
                    __half2 h = __builtin_bit_cast(__half2, S_out[r][wd]);
                    v += hi ? __high2float(h) : __low2float(h);
                }
            } else if (q < 170) {
                #pragma unroll 8
                for (int r = 0; r < 64; ++r)
                    v += __builtin_bit_cast(float, S_out[r][80 + (q - 160)]);
            } else {
                int x = q - 170, b = x >> 4, d = x & 15;
                #pragma unroll
                for (int w2 = 0; w2 < 4; ++w2) {
                    __half2 h = __builtin_bit_cast(__half2, ub_out[w2][b][d >> 1]);
                    v += (d & 1) ? __high2float(h) : __low2float(h);
                }
            }
            unsafeAtomicAdd(&ACC[q], v);
        }
    }
}

// ---------------------------------------------------------------------------
// Reduce block partials: 98 blocks x 16 rows each, atomic fold to ACC
// ---------------------------------------------------------------------------
__global__ __launch_bounds__(256) void caps_reduce(const float* __restrict__ P,
                                                   float* __restrict__ ACC)
{
    const int t = threadIdx.x;
    float acc[5] = {0.f, 0.f, 0.f, 0.f, 0.f};
    const int r0 = blockIdx.x * 16;
    for (int r = 0; r < 16; ++r) {
        const float* row = P + (size_t)(r0 + r) * PSTRIDE;
        #pragma unroll
        for (int s = 0; s < 5; ++s) {
            int col = t + 256 * s;
            float v = (col < ACC_FLOATS) ? row[col] : 0.0f;
            acc[s] += v;
        }
    }
    #pragma unroll
    for (int s = 0; s < 5; ++s) {
        int col = t + 256 * s;
        if (col < ACC_FLOATS) unsafeAtomicAdd(&ACC[col], acc[s]);
    }
}

// ---------------------------------------------------------------------------
// Finalize: dc update + row-normalize, logits = (ubar/Nm)·dc_new, softmax
// ---------------------------------------------------------------------------
__global__ __launch_bounds__(256) void caps_final(const float* __restrict__ ACC,
                                                  const float* __restrict__ dcg,
                                                  float* __restrict__ outp)
{
    __shared__ float dcn[160];
    __shared__ float rnm[10];
    __shared__ float lg[640];
    const int t = threadIdx.x;

    if (t < 160) {
        int c = t >> 4;
        float d0 = dcg[t];
        float upd = (ACC[t] - ACC[160 + c] * d0) * (float)(1.0 / 4014080.0); // /(B*N*m)
        dcn[t] = d0 + upd;
    }
    __syncthreads();
    if (t < 10) {
        float s = 0.0f;
        #pragma unroll
        for (int d = 0; d < 16; ++d) s += dcn[t * 16 + d] * dcn[t * 16 + d];
        rnm[t] = 1.0f / sqrtf(s);
    }
    __syncthreads();
    if (t < 160) dcn[t] *= rnm[t >> 4];
    __syncthreads();

    for (int q = t; q < 640; q += 256) {
        int b = q / 10, c = q - 10 * b;
        const float* ubp = &ACC[170 + b * 16];
        float s = 0.0f;
        #pragma unroll
        for (int d = 0; d < 16; ++d) s += ubp[d] * dcn[c * 16 + d];
        lg[q] = s * (float)(1.0 / 62720.0);   // mean over Nm
    }
    __syncthreads();
    if (t < 64) {
        float mx = lg[t * 10];
        #pragma unroll
        for (int c = 1; c < 10; ++c) mx = fmaxf(mx, lg[t * 10 + c]);
        float e[10];
        float ssum = 0.0f;
        #pragma unroll
        for (int c = 0; c < 10; ++c) { e[c] = expf(lg[t * 10 + c] - mx); ssum += e[c]; }
        float inv = 1.0f / ssum;
        #pragma unroll
        for (int c = 0; c < 10; ++c) outp[t * 10 + c] = e[c] * inv;
    }
}

extern "C" void kernel_launch(void* const* d_in, const int* in_sizes, int n_in,
                              void* d_out, int out_size, void* d_ws, size_t ws_size,
                              hipStream_t stream)
{
    const float* xin = (const float*)d_in[0];
    const float* Wg  = (const float*)d_in[1];
    const float* dcg = (const float*)d_in[2];
    float* outp = (float*)d_out;
    float* ws = (float*)d_ws;
    float* ACC = ws;

    const size_t need = (size_t)(P_OFF + (size_t)NBLK * PSTRIDE) * sizeof(float);
    float* P = (ws_size >= need) ? (ws + P_OFF) : nullptr;

    hipMemsetAsync(ACC, 0, ACC_FLOATS * sizeof(float), stream);
    caps_main<<<dim3(NBLK), dim3(256), 0, stream>>>(xin, Wg, dcg, P, ACC);
    if (P) caps_reduce<<<dim3(98), dim3(256), 0, stream>>>(P, ACC);
    caps_final<<<dim3(1), dim3(256), 0, stream>>>(ACC, dcg, outp);
}

// Round 7
// 176.265 us; speedup vs baseline: 7.2436x; 1.6775x over previous
//
#include <hip/hip_runtime.h>
#include <hip/hip_fp16.h>
#include <math.h>

// Problem constants: B=64, N=14*14*32=6272, DIN=8, D=16, M=10, C=10
#define NPOS 6272
#define DIN_ 8
#define DVEC 16
#define CCAP 10
#define JC 4                    // capsule positions per block (1 per wave)
#define NBLK (NPOS / JC)        // 1568 blocks
#define PSTRIDE 1200            // padded partial row (floats)
#define ACC_FLOATS 1194         // S[160] + T[10] + ubar[64*16]
#define P_OFF 1280              // float offset of partials in ws

// ---------------------------------------------------------------------------
// 4-lane (quad) cross-lane sums via DPP quad_perm -- pure VALU, no LDS.
// ---------------------------------------------------------------------------
__device__ __forceinline__ unsigned qsum_h2(unsigned v) {
    int t = __builtin_amdgcn_mov_dpp((int)v, 0xB1, 0xF, 0xF, true);   // xor 1
    __half2 a = __builtin_bit_cast(__half2, v);
    __half2 b = __builtin_bit_cast(__half2, (unsigned)t);
    a = __hadd2(a, b);
    v = __builtin_bit_cast(unsigned, a);
    t = __builtin_amdgcn_mov_dpp((int)v, 0x4E, 0xF, 0xF, true);        // xor 2
    b = __builtin_bit_cast(__half2, (unsigned)t);
    a = __builtin_bit_cast(__half2, v);
    a = __hadd2(a, b);
    return __builtin_bit_cast(unsigned, a);
}
__device__ __forceinline__ float qsum_f32(float v) {
    int t = __builtin_amdgcn_mov_dpp(__builtin_bit_cast(int, v), 0xB1, 0xF, 0xF, true);
    v += __builtin_bit_cast(float, t);
    t = __builtin_amdgcn_mov_dpp(__builtin_bit_cast(int, v), 0x4E, 0xF, 0xF, true);
    v += __builtin_bit_cast(float, t);
    return v;
}

// tanh(n)/n, branch-free, n >= 0. exp overflow -> rcp(inf)=0 -> tanh=1. OK.
__device__ __forceinline__ float squash_scale(float nsq) {
    float n = __builtin_amdgcn_sqrtf(nsq);
    float e = __expf(2.0f * n);
    float th = 1.0f - 2.0f * __builtin_amdgcn_rcpf(e + 1.0f);
    return th * __builtin_amdgcn_rcpf(n);
}

// ---------------------------------------------------------------------------
// Main kernel. wave = j; lane = b. W staged in LDS (global_load_lds, no VGPR
// round trip); m-loop reads W via 120-cyc broadcast ds_read_b128 instead of
// r6's exposed ~900-cyc HBM broadcast loads. S accumulates in packed-fp16
// registers (80 VGPR); DPP quad-butterfly epilogue; ZERO LDS atomics.
// ---------------------------------------------------------------------------
__global__ __launch_bounds__(256) void caps_main(
    const float* __restrict__ xin,   // [B][N][8]
    const float* __restrict__ Wg,    // [N][8][160]
    const float* __restrict__ dcg,   // [10][16]
    float* __restrict__ P,           // [NBLK][PSTRIDE] or nullptr
    float* __restrict__ ACC)         // [ACC_FLOATS] (atomic fallback)
{
    __shared__ __align__(16) float W_lds[JC * 1280];      // 20480 B
    __shared__ __align__(16) float dc_lds[160];           // 640 B
    __shared__ __align__(16) unsigned S_out[64][90];      // 23040 B
    __shared__ __align__(16) unsigned ub_out[4][64][8];   // 8192 B

    const int tid  = threadIdx.x;
    const int lane = tid & 63;                                  // = b
    const int wvu  = __builtin_amdgcn_readfirstlane(tid >> 6);  // wave id = jj
    const int j0   = blockIdx.x * JC;
    const int j    = j0 + wvu;

    // ---- stage W chunk: async global->LDS, 16 B/lane/issue, linear layout ----
#if __has_builtin(__builtin_amdgcn_global_load_lds)
    {
        const float* gsrc = Wg + (size_t)j0 * 1280;
        #pragma unroll
        for (int s = 0; s < 5; ++s) {
            const int q = tid + s * 256;   // float4 index 0..1279
            __builtin_amdgcn_global_load_lds(
                (const __attribute__((address_space(1))) void*)(gsrc + (size_t)q * 4),
                (__attribute__((address_space(3))) void*)&W_lds[q * 4],
                16, 0, 0);
        }
    }
#else
    {
        const float4* wsrc = (const float4*)(Wg + (size_t)j0 * 1280);
        float4* wdst = (float4*)W_lds;
        #pragma unroll
        for (int s = 0; s < 5; ++s) wdst[tid + 256 * s] = wsrc[tid + 256 * s];
    }
#endif
    if (tid < 40) ((float4*)dc_lds)[tid] = ((const float4*)dcg)[tid];

    // x row (per-lane b, per-wave j): 2 float4 direct from global
    float xr[DIN_];
    {
        const float4* xp = (const float4*)(xin + (size_t)lane * (NPOS * DIN_)
                                               + (size_t)j * DIN_);
        float4 xa = xp[0], xb = xp[1];
        xr[0] = xa.x; xr[1] = xa.y; xr[2] = xa.z; xr[3] = xa.w;
        xr[4] = xb.x; xr[5] = xb.y; xr[6] = xb.z; xr[7] = xb.w;
    }
    __syncthreads();   // drains global_load_lds (vmcnt 0) + publishes dc/W

    // register accumulators
    __half2 S[CCAP][8];                 // 80 VGPRs, packed fp16 pairs
    float   T[CCAP];
    __half2 ub[8];
    #pragma unroll
    for (int c = 0; c < CCAP; ++c) {
        T[c] = 0.0f;
        #pragma unroll
        for (int k = 0; k < 8; ++k) S[c][k] = __float2half2_rn(0.0f);
    }
    #pragma unroll
    for (int k = 0; k < 8; ++k) ub[k] = __float2half2_rn(0.0f);

    const float* wbase = &W_lds[wvu * 1280];

    #pragma unroll 1
    for (int m = 0; m < 10; ++m) {
        // ---- u[16] = x (1x8) @ W[:, m*16..+16)  (broadcast ds_read_b128) ----
        float u[DVEC];
        #pragma unroll
        for (int d = 0; d < DVEC; ++d) u[d] = 0.0f;
        #pragma unroll
        for (int i = 0; i < DIN_; ++i) {
            const float4* wr = (const float4*)(wbase + i * 160 + m * 16);
            float4 a = wr[0], b = wr[1], c = wr[2], d = wr[3];
            float xi = xr[i];
            u[0]  = fmaf(xi, a.x, u[0]);  u[1]  = fmaf(xi, a.y, u[1]);
            u[2]  = fmaf(xi, a.z, u[2]);  u[3]  = fmaf(xi, a.w, u[3]);
            u[4]  = fmaf(xi, b.x, u[4]);  u[5]  = fmaf(xi, b.y, u[5]);
            u[6]  = fmaf(xi, b.z, u[6]);  u[7]  = fmaf(xi, b.w, u[7]);
            u[8]  = fmaf(xi, c.x, u[8]);  u[9]  = fmaf(xi, c.y, u[9]);
            u[10] = fmaf(xi, c.z, u[10]); u[11] = fmaf(xi, c.w, u[11]);
            u[12] = fmaf(xi, d.x, u[12]); u[13] = fmaf(xi, d.y, u[13]);
            u[14] = fmaf(xi, d.z, u[14]); u[15] = fmaf(xi, d.w, u[15]);
        }

        // ---- squash (tree-reduced norm), fp32 ----
        {
            float a0 = fmaf(u[0], u[0], u[1] * u[1]);
            float a1 = fmaf(u[2], u[2], u[3] * u[3]);
            float a2 = fmaf(u[4], u[4], u[5] * u[5]);
            float a3 = fmaf(u[6], u[6], u[7] * u[7]);
            float a4 = fmaf(u[8], u[8], u[9] * u[9]);
            float a5 = fmaf(u[10], u[10], u[11] * u[11]);
            float a6 = fmaf(u[12], u[12], u[13] * u[13]);
            float a7 = fmaf(u[14], u[14], u[15] * u[15]);
            float nsq = ((a0 + a1) + (a2 + a3)) + ((a4 + a5) + (a6 + a7));
            float sc = squash_scale(nsq);
            #pragma unroll
            for (int d = 0; d < DVEC; ++d) u[d] *= sc;
        }

        // ---- pack u to half2; accumulate ub ----
        __half2 uh[8];
        #pragma unroll
        for (int k = 0; k < 8; ++k) {
            uh[k] = __floats2half2_rn(u[2 * k], u[2 * k + 1]);
            ub[k] = __hadd2(ub[k], uh[k]);
        }

        // ---- sims vs 10 digit caps: pure 16-deep fma chains (fp32) ----
        float s[CCAP];
        #pragma unroll
        for (int c = 0; c < CCAP; ++c) {
            const float4* dcr = (const float4*)&dc_lds[c * 16];
            float4 d0 = dcr[0], d1 = dcr[1], d2 = dcr[2], d3 = dcr[3];
            float acc = u[0] * d0.x;
            acc = fmaf(u[1],  d0.y, acc);
            acc = fmaf(u[2],  d0.z, acc);
            acc = fmaf(u[3],  d0.w, acc);
            acc = fmaf(u[4],  d1.x, acc);
            acc = fmaf(u[5],  d1.y, acc);
            acc = fmaf(u[6],  d1.z, acc);
            acc = fmaf(u[7],  d1.w, acc);
            acc = fmaf(u[8],  d2.x, acc);
            acc = fmaf(u[9],  d2.y, acc);
            acc = fmaf(u[10], d2.z, acc);
            acc = fmaf(u[11], d2.w, acc);
            acc = fmaf(u[12], d3.x, acc);
            acc = fmaf(u[13], d3.y, acc);
            acc = fmaf(u[14], d3.z, acc);
            acc = fmaf(u[15], d3.w, acc);
            s[c] = acc;
        }

        // ---- exact reference winner semantics (mask in {1,0,-1} bitmasks) ----
        int win0, win1, win2;
        {
            unsigned once = 0, twice = 0;
            #pragma unroll
            for (int t = 0; t < 3; ++t) {
                float best = -1e30f;
                int win = 0;
                #pragma unroll
                for (int c = 0; c < CCAP; ++c) {
                    float sv = s[c];
                    float v = (once & (1u << c)) ? ((twice & (1u << c)) ? -sv : 0.0f) : sv;
                    if (v > best) { best = v; win = c; }
                }
                twice |= (once & (1u << win));
                once  |= (1u << win);
                if (t == 0) win0 = win; else if (t == 1) win1 = win; else win2 = win;
            }
        }

        // ---- dense weighted accumulate in packed fp16 ----
        #pragma unroll
        for (int c = 0; c < CCAP; ++c) {
            float w = (win0 == c ? 1.0f : 0.0f);
            w += (win1 == c) ? 0.2f : 0.0f;
            w += (win2 == c) ? 0.1f : 0.0f;
            T[c] += w;
            __half2 wh = __float2half2_rn(w);
            #pragma unroll
            for (int k = 0; k < 8; ++k) S[c][k] = __hfma2(wh, uh[k], S[c][k]);
        }
    }

    // ---- quad-butterfly (DPP, VALU-only) then plain LDS writes ----
    {
        unsigned sq[CCAP][8];
        float tq[CCAP];
        #pragma unroll
        for (int c = 0; c < CCAP; ++c) {
            tq[c] = qsum_f32(T[c]);
            #pragma unroll
            for (int k = 0; k < 8; ++k)
                sq[c][k] = qsum_h2(__builtin_bit_cast(unsigned, S[c][k]));
        }
        if ((lane & 3) == 0) {
            unsigned* row = S_out[wvu * 16 + (lane >> 2)];
            #pragma unroll
            for (int c = 0; c < CCAP; ++c) {
                #pragma unroll
                for (int k = 0; k < 8; ++k) row[c * 8 + k] = sq[c][k];
                row[80 + c] = __builtin_bit_cast(unsigned, tq[c]);
            }
        }
        #pragma unroll
        for (int k = 0; k < 8; ++k)
            ub_out[wvu][lane][k] = __builtin_bit_cast(unsigned, ub[k]);
    }
    __syncthreads();

    // ---- fold 64 quad-replicas + 4 ub waves, emit 1194 fp32 partials ----
    if (P != nullptr) {
        float* prow = P + (size_t)blockIdx.x * PSTRIDE;
        for (int q = tid; q < ACC_FLOATS; q += 256) {
            float v = 0.0f;
            if (q < 160) {
                int wd = (q >> 4) * 8 + ((q & 15) >> 1);
                int hi = q & 1;
                #pragma unroll 8
                for (int r = 0; r < 64; ++r) {
                    __half2 h = __builtin_bit_cast(__half2, S_out[r][wd]);
                    v += hi ? __high2float(h) : __low2float(h);
                }
            } else if (q < 170) {
                #pragma unroll 8
                for (int r = 0; r < 64; ++r)
                    v += __builtin_bit_cast(float, S_out[r][80 + (q - 160)]);
            } else {
                int x = q - 170, b = x >> 4, d = x & 15;
                #pragma unroll
                for (int w2 = 0; w2 < 4; ++w2) {
                    __half2 h = __builtin_bit_cast(__half2, ub_out[w2][b][d >> 1]);
                    v += (d & 1) ? __high2float(h) : __low2float(h);
                }
            }
            prow[q] = v;
        }
    } else {
        for (int q = tid; q < ACC_FLOATS; q += 256) {
            float v = 0.0f;
            if (q < 160) {
                int wd = (q >> 4) * 8 + ((q & 15) >> 1);
                int hi = q & 1;
                #pragma unroll 8
                for (int r = 0; r < 64; ++r) {
                    __half2 h = __builtin_bit_cast(__half2, S_out[r][wd]);
                    v += hi ? __high2float(h) : __low2float(h);
                }
            } else if (q < 170) {
                #pragma unroll 8
                for (int r = 0; r < 64; ++r)
                    v += __builtin_bit_cast(float, S_out[r][80 + (q - 160)]);
            } else {
                int x = q - 170, b = x >> 4, d = x & 15;
                #pragma unroll
                for (int w2 = 0; w2 < 4; ++w2) {
                    __half2 h = __builtin_bit_cast(__half2, ub_out[w2][b][d >> 1]);
                    v += (d & 1) ? __high2float(h) : __low2float(h);
                }
            }
            unsafeAtomicAdd(&ACC[q], v);
        }
    }
}

// ---------------------------------------------------------------------------
// Reduce block partials: 98 blocks x 16 rows each, atomic fold to ACC
// ---------------------------------------------------------------------------
__global__ __launch_bounds__(256) void caps_reduce(const float* __restrict__ P,
                                                   float* __restrict__ ACC)
{
    const int t = threadIdx.x;
    float acc[5] = {0.f, 0.f, 0.f, 0.f, 0.f};
    const int r0 = blockIdx.x * 16;
    for (int r = 0; r < 16; ++r) {
        const float* row = P + (size_t)(r0 + r) * PSTRIDE;
        #pragma unroll
        for (int s = 0; s < 5; ++s) {
            int col = t + 256 * s;
            float v = (col < ACC_FLOATS) ? row[col] : 0.0f;
            acc[s] += v;
        }
    }
    #pragma unroll
    for (int s = 0; s < 5; ++s) {
        int col = t + 256 * s;
        if (col < ACC_FLOATS) unsafeAtomicAdd(&ACC[col], acc[s]);
    }
}

// ---------------------------------------------------------------------------
// Finalize: dc update + row-normalize, logits = (ubar/Nm)·dc_new, softmax
// ---------------------------------------------------------------------------
__global__ __launch_bounds__(256) void caps_final(const float* __restrict__ ACC,
                                                  const float* __restrict__ dcg,
                                                  float* __restrict__ outp)
{
    __shared__ float dcn[160];
    __shared__ float rnm[10];
    __shared__ float lg[640];
    const int t = threadIdx.x;

    if (t < 160) {
        int c = t >> 4;
        float d0 = dcg[t];
        float upd = (ACC[t] - ACC[160 + c] * d0) * (float)(1.0 / 4014080.0); // /(B*N*m)
        dcn[t] = d0 + upd;
    }
    __syncthreads();
    if (t < 10) {
        float s = 0.0f;
        #pragma unroll
        for (int d = 0; d < 16; ++d) s += dcn[t * 16 + d] * dcn[t * 16 + d];
        rnm[t] = 1.0f / sqrtf(s);
    }
    __syncthreads();
    if (t < 160) dcn[t] *= rnm[t >> 4];
    __syncthreads();

    for (int q = t; q < 640; q += 256) {
        int b = q / 10, c = q - 10 * b;
        const float* ubp = &ACC[170 + b * 16];
        float s = 0.0f;
        #pragma unroll
        for (int d = 0; d < 16; ++d) s += ubp[d] * dcn[c * 16 + d];
        lg[q] = s * (float)(1.0 / 62720.0);   // mean over Nm
    }
    __syncthreads();
    if (t < 64) {
        float mx = lg[t * 10];
        #pragma unroll
        for (int c = 1; c < 10; ++c) mx = fmaxf(mx, lg[t * 10 + c]);
        float e[10];
        float ssum = 0.0f;
        #pragma unroll
        for (int c = 0; c < 10; ++c) { e[c] = expf(lg[t * 10 + c] - mx); ssum += e[c]; }
        float inv = 1.0f / ssum;
        #pragma unroll
        for (int c = 0; c < 10; ++c) outp[t * 10 + c] = e[c] * inv;
    }
}

extern "C" void kernel_launch(void* const* d_in, const int* in_sizes, int n_in,
                              void* d_out, int out_size, void* d_ws, size_t ws_size,
                              hipStream_t stream)
{
    const float* xin = (const float*)d_in[0];
    const float* Wg  = (const float*)d_in[1];
    const float* dcg = (const float*)d_in[2];
    float* outp = (float*)d_out;
    float* ws = (float*)d_ws;
    float* ACC = ws;

    const size_t need = (size_t)(P_OFF + (size_t)NBLK * PSTRIDE) * sizeof(float);
    float* P = (ws_size >= need) ? (ws + P_OFF) : nullptr;

    hipMemsetAsync(ACC, 0, ACC_FLOATS * sizeof(float), stream);
    caps_main<<<dim3(NBLK), dim3(256), 0, stream>>>(xin, Wg, dcg, P, ACC);
    if (P) caps_reduce<<<dim3(98), dim3(256), 0, stream>>>(P, ACC);
    caps_final<<<dim3(1), dim3(256), 0, stream>>>(ACC, dcg, outp);
}

// Round 8
// 108.918 us; speedup vs baseline: 11.7224x; 1.6183x over previous
//
#include <hip/hip_runtime.h>
#include <hip/hip_fp16.h>
#include <math.h>

// Problem constants: B=64, N=14*14*32=6272, DIN=8, D=16, M=10, C=10
#define NPOS 6272
#define DIN_ 8
#define DVEC 16
#define CCAP 10
#define JC 4                    // capsule positions per block (1 per wave)
#define NBLK (NPOS / JC)        // 1568 blocks
#define PSTRIDE 1200            // padded partial row (floats)
#define ACC_FLOATS 1194         // S[160] + T[10] + ubar[64*16]
#define P_OFF 1280              // float offset of partials in ws
#define SH_WORDS 5760           // union region: W_h2 (2560 w) / S_out 64x90 (5760 w)

// packed-fp16 dot: c += a.x*b.x + a.y*b.y (f32 accumulate)
__device__ __forceinline__ float fdot2u(unsigned a, unsigned b, float c) {
#if __has_builtin(__builtin_amdgcn_fdot2)
    typedef _Float16 h2v __attribute__((ext_vector_type(2)));
    return __builtin_amdgcn_fdot2(__builtin_bit_cast(h2v, a),
                                  __builtin_bit_cast(h2v, b), c, false);
#else
    __half2 p = __hmul2(__builtin_bit_cast(__half2, a), __builtin_bit_cast(__half2, b));
    return c + (__low2float(p) + __high2float(p));
#endif
}
__device__ __forceinline__ unsigned pack_rn(float lo, float hi) {
    return __builtin_bit_cast(unsigned, __floats2half2_rn(lo, hi));
}

// 4-lane (quad) cross-lane sums via DPP quad_perm -- pure VALU, no LDS.
__device__ __forceinline__ unsigned qsum_h2(unsigned v) {
    int t = __builtin_amdgcn_mov_dpp((int)v, 0xB1, 0xF, 0xF, true);   // xor 1
    __half2 a = __builtin_bit_cast(__half2, v);
    __half2 b = __builtin_bit_cast(__half2, (unsigned)t);
    a = __hadd2(a, b);
    v = __builtin_bit_cast(unsigned, a);
    t = __builtin_amdgcn_mov_dpp((int)v, 0x4E, 0xF, 0xF, true);        // xor 2
    b = __builtin_bit_cast(__half2, (unsigned)t);
    a = __builtin_bit_cast(__half2, v);
    a = __hadd2(a, b);
    return __builtin_bit_cast(unsigned, a);
}
__device__ __forceinline__ float qsum_f32(float v) {
    int t = __builtin_amdgcn_mov_dpp(__builtin_bit_cast(int, v), 0xB1, 0xF, 0xF, true);
    v += __builtin_bit_cast(float, t);
    t = __builtin_amdgcn_mov_dpp(__builtin_bit_cast(int, v), 0x4E, 0xF, 0xF, true);
    v += __builtin_bit_cast(float, t);
    return v;
}

// tanh(n)/n, branch-free, n >= 0. exp overflow -> rcp(inf)=0 -> tanh=1. OK.
__device__ __forceinline__ float squash_scale(float nsq) {
    float n = __builtin_amdgcn_sqrtf(nsq);
    float e = __expf(2.0f * n);
    float th = 1.0f - 2.0f * __builtin_amdgcn_rcpf(e + 1.0f);
    return th * __builtin_amdgcn_rcpf(n);
}

// ---------------------------------------------------------------------------
// Main kernel. wave = j; lane = b. fp16 everywhere the data moves, f32 where
// it accumulates: W/x/dc in packed half2 (halves LDS-pipe b128 count 72->36
// per iter and VALU fma count 288->144 via v_dot2_f32_f16); u/squash/argmax
// in f32; S in packed-fp16 regs; DPP quad epilogue; zero LDS atomics.
// LDS union: S_out overlays the dead W region after the m-loop (52.7->31.5KB).
// ---------------------------------------------------------------------------
__global__ __launch_bounds__(256) void caps_main(
    const float* __restrict__ xin,   // [B][N][8]
    const float* __restrict__ Wg,    // [N][8][160]
    const float* __restrict__ dcg,   // [10][16]
    float* __restrict__ P,           // [NBLK][PSTRIDE] or nullptr
    float* __restrict__ ACC)         // [ACC_FLOATS] (atomic fallback)
{
    __shared__ __align__(16) unsigned SH[SH_WORDS];       // 23040 B (W_h2 / S_out union)
    __shared__ __align__(16) unsigned dch[84];            // 80 half2 words (dc)
    __shared__ __align__(16) unsigned ub_out[4][64][8];   // 8192 B

    const int tid  = threadIdx.x;
    const int lane = tid & 63;                                  // = b
    const int wvu  = __builtin_amdgcn_readfirstlane(tid >> 6);  // wave id = jj
    const int j0   = blockIdx.x * JC;
    const int j    = j0 + wvu;

    // ---- stage W as half2, i-pair interleaved: W_h2[jk][d] = (W[2k][d], W[2k+1][d]) ----
    for (int g = tid; g < 640; g += 256) {
        int jk = g / 40, d4 = g - jk * 40;      // jk = jj*4+k, d4 = d/4
        int jj = jk >> 2, k = jk & 3;
        const float* s1 = Wg + (size_t)(j0 + jj) * 1280 + (2 * k) * 160 + d4 * 4;
        float4 a = *(const float4*)s1;
        float4 b = *(const float4*)(s1 + 160);
        uint4 w;
        w.x = pack_rn(a.x, b.x); w.y = pack_rn(a.y, b.y);
        w.z = pack_rn(a.z, b.z); w.w = pack_rn(a.w, b.w);
        *(uint4*)(SH + jk * 160 + d4 * 4) = w;
    }
    // ---- stage dc as half2 (d-pairs) ----
    if (tid < 20) {
        int c = tid >> 1, part = tid & 1;
        const float4* dp = (const float4*)(dcg + c * 16 + part * 8);
        float4 a = dp[0], b = dp[1];
        uint4 w;
        w.x = pack_rn(a.x, a.y); w.y = pack_rn(a.z, a.w);
        w.z = pack_rn(b.x, b.y); w.w = pack_rn(b.z, b.w);
        *(uint4*)(dch + c * 8 + part * 4) = w;
    }

    // ---- x row (per-lane b, per-wave j) -> 4 packed half2 (i-pairs) ----
    unsigned xh[4];
    {
        const float4* xp = (const float4*)(xin + (size_t)lane * (NPOS * DIN_)
                                               + (size_t)j * DIN_);
        float4 xa = xp[0], xb = xp[1];
        xh[0] = pack_rn(xa.x, xa.y); xh[1] = pack_rn(xa.z, xa.w);
        xh[2] = pack_rn(xb.x, xb.y); xh[3] = pack_rn(xb.z, xb.w);
    }
    __syncthreads();   // staging visible to all waves

    // register accumulators
    __half2 S[CCAP][8];                 // 80 VGPRs, packed fp16 pairs
    float   T[CCAP];
    __half2 ub[8];
    #pragma unroll
    for (int c = 0; c < CCAP; ++c) {
        T[c] = 0.0f;
        #pragma unroll
        for (int k = 0; k < 8; ++k) S[c][k] = __float2half2_rn(0.0f);
    }
    #pragma unroll
    for (int k = 0; k < 8; ++k) ub[k] = __float2half2_rn(0.0f);

    const unsigned* wbase = SH + wvu * 640;

    #pragma unroll 1
    for (int m = 0; m < 10; ++m) {
        // ---- u[16] = x (1x8) @ W[:, m*16..+16): 16 b128 + 64 fdot2 ----
        float u[DVEC];
        #pragma unroll
        for (int d = 0; d < DVEC; ++d) u[d] = 0.0f;
        #pragma unroll
        for (int k = 0; k < 4; ++k) {
            const uint4* wk = (const uint4*)(wbase + k * 160 + m * 16);
            uint4 q0 = wk[0], q1 = wk[1], q2 = wk[2], q3 = wk[3];
            unsigned xk = xh[k];
            u[0]  = fdot2u(xk, q0.x, u[0]);  u[1]  = fdot2u(xk, q0.y, u[1]);
            u[2]  = fdot2u(xk, q0.z, u[2]);  u[3]  = fdot2u(xk, q0.w, u[3]);
            u[4]  = fdot2u(xk, q1.x, u[4]);  u[5]  = fdot2u(xk, q1.y, u[5]);
            u[6]  = fdot2u(xk, q1.z, u[6]);  u[7]  = fdot2u(xk, q1.w, u[7]);
            u[8]  = fdot2u(xk, q2.x, u[8]);  u[9]  = fdot2u(xk, q2.y, u[9]);
            u[10] = fdot2u(xk, q2.z, u[10]); u[11] = fdot2u(xk, q2.w, u[11]);
            u[12] = fdot2u(xk, q3.x, u[12]); u[13] = fdot2u(xk, q3.y, u[13]);
            u[14] = fdot2u(xk, q3.z, u[14]); u[15] = fdot2u(xk, q3.w, u[15]);
        }

        // ---- squash (tree-reduced norm), f32 ----
        {
            float a0 = fmaf(u[0], u[0], u[1] * u[1]);
            float a1 = fmaf(u[2], u[2], u[3] * u[3]);
            float a2 = fmaf(u[4], u[4], u[5] * u[5]);
            float a3 = fmaf(u[6], u[6], u[7] * u[7]);
            float a4 = fmaf(u[8], u[8], u[9] * u[9]);
            float a5 = fmaf(u[10], u[10], u[11] * u[11]);
            float a6 = fmaf(u[12], u[12], u[13] * u[13]);
            float a7 = fmaf(u[14], u[14], u[15] * u[15]);
            float nsq = ((a0 + a1) + (a2 + a3)) + ((a4 + a5) + (a6 + a7));
            float sc = squash_scale(nsq);
            #pragma unroll
            for (int d = 0; d < DVEC; ++d) u[d] *= sc;
        }

        // ---- pack u to half2; accumulate ub ----
        unsigned uh[8];
        #pragma unroll
        for (int k = 0; k < 8; ++k) {
            uh[k] = pack_rn(u[2 * k], u[2 * k + 1]);
            ub[k] = __hadd2(ub[k], __builtin_bit_cast(__half2, uh[k]));
        }

        // ---- sims vs 10 digit caps: 2 b128 + 8 fdot2 per class ----
        float s[CCAP];
        #pragma unroll
        for (int c = 0; c < CCAP; ++c) {
            const uint4* dq = (const uint4*)(dch + c * 8);
            uint4 e0 = dq[0], e1 = dq[1];
            float acc = fdot2u(uh[0], e0.x, 0.0f);
            acc = fdot2u(uh[1], e0.y, acc);
            acc = fdot2u(uh[2], e0.z, acc);
            acc = fdot2u(uh[3], e0.w, acc);
            acc = fdot2u(uh[4], e1.x, acc);
            acc = fdot2u(uh[5], e1.y, acc);
            acc = fdot2u(uh[6], e1.z, acc);
            acc = fdot2u(uh[7], e1.w, acc);
            s[c] = acc;
        }

        // ---- exact reference winner semantics (mask in {1,0,-1} bitmasks) ----
        int win0, win1, win2;
        {
            unsigned once = 0, twice = 0;
            #pragma unroll
            for (int t = 0; t < 3; ++t) {
                float best = -1e30f;
                int win = 0;
                #pragma unroll
                for (int c = 0; c < CCAP; ++c) {
                    float sv = s[c];
                    float v = (once & (1u << c)) ? ((twice & (1u << c)) ? -sv : 0.0f) : sv;
                    if (v > best) { best = v; win = c; }
                }
                twice |= (once & (1u << win));
                once  |= (1u << win);
                if (t == 0) win0 = win; else if (t == 1) win1 = win; else win2 = win;
            }
        }

        // ---- dense weighted accumulate in packed fp16 ----
        #pragma unroll
        for (int c = 0; c < CCAP; ++c) {
            float w = (win0 == c ? 1.0f : 0.0f);
            w += (win1 == c) ? 0.2f : 0.0f;
            w += (win2 == c) ? 0.1f : 0.0f;
            T[c] += w;
            __half2 wh = __float2half2_rn(w);
            #pragma unroll
            for (int k = 0; k < 8; ++k)
                S[c][k] = __hfma2(wh, __builtin_bit_cast(__half2, uh[k]), S[c][k]);
        }
    }

    __syncthreads();   // W region dead for ALL waves before S_out overlays it

    // ---- quad-butterfly (DPP, VALU-only) then plain LDS writes ----
    {
        unsigned sq[CCAP][8];
        float tq[CCAP];
        #pragma unroll
        for (int c = 0; c < CCAP; ++c) {
            tq[c] = qsum_f32(T[c]);
            #pragma unroll
            for (int k = 0; k < 8; ++k)
                sq[c][k] = qsum_h2(__builtin_bit_cast(unsigned, S[c][k]));
        }
        if ((lane & 3) == 0) {
            unsigned* row = SH + (wvu * 16 + (lane >> 2)) * 90;
            #pragma unroll
            for (int c = 0; c < CCAP; ++c) {
                #pragma unroll
                for (int k = 0; k < 8; ++k) row[c * 8 + k] = sq[c][k];
                row[80 + c] = __builtin_bit_cast(unsigned, tq[c]);
            }
        }
        #pragma unroll
        for (int k = 0; k < 8; ++k)
            ub_out[wvu][lane][k] = __builtin_bit_cast(unsigned, ub[k]);
    }
    __syncthreads();

    // ---- fold 64 quad-replicas + 4 ub waves, emit 1194 fp32 partials ----
    if (P != nullptr) {
        float* prow = P + (size_t)blockIdx.x * PSTRIDE;
        for (int q = tid; q < ACC_FLOATS; q += 256) {
            float v = 0.0f;
            if (q < 160) {
                int wd = (q >> 4) * 8 + ((q & 15) >> 1);
                int hi = q & 1;
                #pragma unroll 8
                for (int r = 0; r < 64; ++r) {
                    __half2 h = __builtin_bit_cast(__half2, SH[r * 90 + wd]);
                    v += hi ? __high2float(h) : __low2float(h);
                }
            } else if (q < 170) {
                #pragma unroll 8
                for (int r = 0; r < 64; ++r)
                    v += __builtin_bit_cast(float, SH[r * 90 + 80 + (q - 160)]);
            } else {
                int x = q - 170, b = x >> 4, d = x & 15;
                #pragma unroll
                for (int w2 = 0; w2 < 4; ++w2) {
                    __half2 h = __builtin_bit_cast(__half2, ub_out[w2][b][d >> 1]);
                    v += (d & 1) ? __high2float(h) : __low2float(h);
                }
            }
            prow[q] = v;
        }
    } else {
        for (int q = tid; q < ACC_FLOATS; q += 256) {
            float v = 0.0f;
            if (q < 160) {
                int wd = (q >> 4) * 8 + ((q & 15) >> 1);
                int hi = q & 1;
                #pragma unroll 8
                for (int r = 0; r < 64; ++r) {
                    __half2 h = __builtin_bit_cast(__half2, SH[r * 90 + wd]);
                    v += hi ? __high2float(h) : __low2float(h);
                }
            } else if (q < 170) {
                #pragma unroll 8
                for (int r = 0; r < 64; ++r)
                    v += __builtin_bit_cast(float, SH[r * 90 + 80 + (q - 160)]);
            } else {
                int x = q - 170, b = x >> 4, d = x & 15;
                #pragma unroll
                for (int w2 = 0; w2 < 4; ++w2) {
                    __half2 h = __builtin_bit_cast(__half2, ub_out[w2][b][d >> 1]);
                    v += (d & 1) ? __high2float(h) : __low2float(h);
                }
            }
            unsafeAtomicAdd(&ACC[q], v);
        }
    }
}

// ---------------------------------------------------------------------------
// Reduce block partials: 98 blocks x 16 rows each, atomic fold to ACC
// ---------------------------------------------------------------------------
__global__ __launch_bounds__(256) void caps_reduce(const float* __restrict__ P,
                                                   float* __restrict__ ACC)
{
    const int t = threadIdx.x;
    float acc[5] = {0.f, 0.f, 0.f, 0.f, 0.f};
    const int r0 = blockIdx.x * 16;
    for (int r = 0; r < 16; ++r) {
        const float* row = P + (size_t)(r0 + r) * PSTRIDE;
        #pragma unroll
        for (int s = 0; s < 5; ++s) {
            int col = t + 256 * s;
            float v = (col < ACC_FLOATS) ? row[col] : 0.0f;
            acc[s] += v;
        }
    }
    #pragma unroll
    for (int s = 0; s < 5; ++s) {
        int col = t + 256 * s;
        if (col < ACC_FLOATS) unsafeAtomicAdd(&ACC[col], acc[s]);
    }
}

// ---------------------------------------------------------------------------
// Finalize: dc update + row-normalize, logits = (ubar/Nm)·dc_new, softmax
// ---------------------------------------------------------------------------
__global__ __launch_bounds__(256) void caps_final(const float* __restrict__ ACC,
                                                  const float* __restrict__ dcg,
                                                  float* __restrict__ outp)
{
    __shared__ float dcn[160];
    __shared__ float rnm[10];
    __shared__ float lg[640];
    const int t = threadIdx.x;

    if (t < 160) {
        int c = t >> 4;
        float d0 = dcg[t];
        float upd = (ACC[t] - ACC[160 + c] * d0) * (float)(1.0 / 4014080.0); // /(B*N*m)
        dcn[t] = d0 + upd;
    }
    __syncthreads();
    if (t < 10) {
        float s = 0.0f;
        #pragma unroll
        for (int d = 0; d < 16; ++d) s += dcn[t * 16 + d] * dcn[t * 16 + d];
        rnm[t] = 1.0f / sqrtf(s);
    }
    __syncthreads();
    if (t < 160) dcn[t] *= rnm[t >> 4];
    __syncthreads();

    for (int q = t; q < 640; q += 256) {
        int b = q / 10, c = q - 10 * b;
        const float* ubp = &ACC[170 + b * 16];
        float s = 0.0f;
        #pragma unroll
        for (int d = 0; d < 16; ++d) s += ubp[d] * dcn[c * 16 + d];
        lg[q] = s * (float)(1.0 / 62720.0);   // mean over Nm
    }
    __syncthreads();
    if (t < 64) {
        float mx = lg[t * 10];
        #pragma unroll
        for (int c = 1; c < 10; ++c) mx = fmaxf(mx, lg[t * 10 + c]);
        float e[10];
        float ssum = 0.0f;
        #pragma unroll
        for (int c = 0; c < 10; ++c) { e[c] = expf(lg[t * 10 + c] - mx); ssum += e[c]; }
        float inv = 1.0f / ssum;
        #pragma unroll
        for (int c = 0; c < 10; ++c) outp[t * 10 + c] = e[c] * inv;
    }
}

extern "C" void kernel_launch(void* const* d_in, const int* in_sizes, int n_in,
                              void* d_out, int out_size, void* d_ws, size_t ws_size,
                              hipStream_t stream)
{
    const float* xin = (const float*)d_in[0];
    const float* Wg  = (const float*)d_in[1];
    const float* dcg = (const float*)d_in[2];
    float* outp = (float*)d_out;
    float* ws = (float*)d_ws;
    float* ACC = ws;

    const size_t need = (size_t)(P_OFF + (size_t)NBLK * PSTRIDE) * sizeof(float);
    float* P = (ws_size >= need) ? (ws + P_OFF) : nullptr;

    hipMemsetAsync(ACC, 0, ACC_FLOATS * sizeof(float), stream);
    caps_main<<<dim3(NBLK), dim3(256), 0, stream>>>(xin, Wg, dcg, P, ACC);
    if (P) caps_reduce<<<dim3(98), dim3(256), 0, stream>>>(P, ACC);
    caps_final<<<dim3(1), dim3(256), 0, stream>>>(ACC, dcg, outp);
}